// Round 13
// baseline (208.311 us; speedup 1.0000x reference)
//
#include <hip/hip_runtime.h>
#include <math.h>

// Problem constants
#define TT 2048
#define EE 1024
#define HH 16
#define DH 64

typedef unsigned short u16;
typedef __attribute__((ext_vector_type(8))) short bf16x8;   // 8 bf16 = 4 VGPRs
typedef __attribute__((ext_vector_type(4))) float f32x4;
typedef __attribute__((address_space(1))) unsigned int uint_g;
typedef __attribute__((address_space(3))) unsigned int uint_l;

// fp32 -> bf16 round-to-nearest-even
__device__ __forceinline__ u16 f2bf(float f) {
  unsigned u = __float_as_uint(f);
  u += 0x7fffu + ((u >> 16) & 1u);
  return (u16)(u >> 16);
}
__device__ __forceinline__ float bf2f(u16 v) {
  return __uint_as_float(((unsigned)v) << 16);
}

// ---------------------------------------------------------------------------
// Fused fp32 -> bf16 conversion of x, W1, W2 (one launch).
// ---------------------------------------------------------------------------
__global__ __launch_bounds__(256) void cvt_all(
    const float* __restrict__ x, const float* __restrict__ W1,
    const float* __restrict__ W2, u16* __restrict__ xb, u16* __restrict__ w1b,
    u16* __restrict__ w2b) {
  int i = blockIdx.x * 256 + threadIdx.x;  // < 786432
  const float* s;
  u16* d;
  if (i < 262144) {
    s = x; d = xb;
  } else if (i < 262144 + 393216) {
    i -= 262144; s = W1; d = w1b;
  } else {
    i -= 262144 + 393216; s = W2; d = w2b;
  }
  const float4* s4 = (const float4*)s;
  float4 a = s4[2 * i], b = s4[2 * i + 1];
  bf16x8 o;
  o[0] = (short)f2bf(a.x); o[1] = (short)f2bf(a.y);
  o[2] = (short)f2bf(a.z); o[3] = (short)f2bf(a.w);
  o[4] = (short)f2bf(b.x); o[5] = (short)f2bf(b.y);
  o[6] = (short)f2bf(b.z); o[7] = (short)f2bf(b.w);
  *(bf16x8*)&d[8 * i] = o;
}

// ---------------------------------------------------------------------------
// RoPE cos/sin table: [T][32].
// ---------------------------------------------------------------------------
__global__ void rope_table(float* __restrict__ cs, float* __restrict__ sn) {
  int i = blockIdx.x * 256 + threadIdx.x;  // < 2048*32
  int t = i >> 5;
  int d = i & 31;
  float inv = powf(10000.f, -((float)d) / 32.f);
  float ang = (float)t * inv;
  cs[i] = (float)cos((double)ang);
  sn[i] = (float)sin((double)ang);
}

// ---------------------------------------------------------------------------
// bf16 MFMA GEMM (TN): C[m][n] = sum_k A[m][k] * B[n][k], fp32 accum.
// 128x128 tile, BK=32, 256 threads = 4 waves (2x2), 4x4 16x16x32 frags/wave.
// EPI==0: row-major fp32 C.
// EPI==1: QKV epilogue — q,k: fused RoPE, bf16 [H][T][DH]; v: bf16 [H][DH][T].
// ---------------------------------------------------------------------------
template <int EPI>
__global__ __launch_bounds__(256) void gemm_mfma(
    const u16* __restrict__ A, const u16* __restrict__ B, float* __restrict__ C,
    u16* __restrict__ q16, u16* __restrict__ k16, u16* __restrict__ vt,
    const float* __restrict__ cs, const float* __restrict__ sn, int M, int N,
    int K) {
  __shared__ u16 smem[8192];  // As[128][32] @0 | Bs[128][32] @4096 (ushorts)
  const int tid = threadIdx.x;
  const int lane = tid & 63;
  const int wid = tid >> 6;
  const int wr = wid >> 1, wc = wid & 1;
  const int m0 = blockIdx.y * 128, n0 = blockIdx.x * 128;

  const u16* gp[4];
  int lo[4];
#pragma unroll
  for (int q = 0; q < 4; q++) {
    int o = (wid * 4 + q) * 1024 + lane * 16;  // byte offset into smem
    lo[q] = o >> 1;
    if (o < 8192) {
      int row = o >> 6, col = (o >> 1) & 31;
      gp[q] = A + (size_t)(m0 + row) * K + col;
    } else {
      int o2 = o - 8192;
      int row = o2 >> 6, col = (o2 >> 1) & 31;
      gp[q] = B + (size_t)(n0 + row) * K + col;
    }
  }

  const int a_off = (wr * 64 + (lane & 15)) * 32 + (lane >> 4) * 8;
  const int b_off = 4096 + (wc * 64 + (lane & 15)) * 32 + (lane >> 4) * 8;

  f32x4 acc[4][4];
#pragma unroll
  for (int i = 0; i < 4; i++)
#pragma unroll
    for (int j = 0; j < 4; j++) acc[i][j] = f32x4{0.f, 0.f, 0.f, 0.f};

  for (int k0 = 0; k0 < K; k0 += 32) {
    __syncthreads();
#pragma unroll
    for (int q = 0; q < 4; q++) {
      __builtin_amdgcn_global_load_lds((const uint_g*)gp[q],
                                       (uint_l*)&smem[lo[q]], 16, 0, 0);
      gp[q] += 32;
    }
    __syncthreads();
    bf16x8 af[4], bg[4];
#pragma unroll
    for (int i = 0; i < 4; i++) af[i] = *(const bf16x8*)&smem[a_off + i * 512];
#pragma unroll
    for (int j = 0; j < 4; j++) bg[j] = *(const bf16x8*)&smem[b_off + j * 512];
#pragma unroll
    for (int i = 0; i < 4; i++)
#pragma unroll
      for (int j = 0; j < 4; j++)
        acc[i][j] = __builtin_amdgcn_mfma_f32_16x16x32_bf16(af[i], bg[j],
                                                            acc[i][j], 0, 0, 0);
  }

  // epilogue: C/D layout col(n)=lane&15, row(m)=(lane>>4)*4+reg
  const int rbase = (lane >> 4) * 4;
  const int ncol = lane & 15;
  if (EPI == 0) {
#pragma unroll
    for (int i = 0; i < 4; i++) {
      int m = m0 + wr * 64 + i * 16 + rbase;
#pragma unroll
      for (int j = 0; j < 4; j++) {
        int n = n0 + wc * 64 + j * 16 + ncol;
#pragma unroll
        for (int r = 0; r < 4; r++) C[(size_t)(m + r) * N + n] = acc[i][j][r];
      }
    }
  } else {
    const int which = n0 >> 10;  // uniform per block
    if (which == 2) {
      // v: transposed bf16 [H][DH][T]
#pragma unroll
      for (int j = 0; j < 4; j++) {
        int n = n0 + wc * 64 + j * 16 + ncol;
        int h = (n >> 6) & 15, d = n & 63;
#pragma unroll
        for (int i = 0; i < 4; i++) {
          int m = m0 + wr * 64 + i * 16 + rbase;
#pragma unroll
          for (int r = 0; r < 4; r++)
            vt[((size_t)h * DH + d) * TT + m + r] = f2bf(acc[i][j][r]);
        }
      }
    } else {
      // q,k: fused RoPE (pairs (j, j+2) hold dims (d, d+32), d<32), bf16 out
      u16* dst = (which == 0) ? q16 : k16;
#pragma unroll
      for (int j = 0; j < 2; j++) {
        int n = n0 + wc * 64 + j * 16 + ncol;
        int h = (n >> 6) & 15, d = n & 63;  // d < 32
#pragma unroll
        for (int i = 0; i < 4; i++) {
          int mrow = m0 + wr * 64 + i * 16 + rbase;
#pragma unroll
          for (int r = 0; r < 4; r++) {
            int t = mrow + r;
            float c = cs[t * 32 + d];
            float s = sn[t * 32 + d];
            float a = acc[i][j][r];
            float b = acc[i][j + 2][r];
            size_t off = ((size_t)h * TT + t) * DH + d;
            dst[off] = f2bf(a * c - b * s);
            dst[off + 32] = f2bf(b * c + a * s);
          }
        }
      }
    }
  }
}

// ---------------------------------------------------------------------------
// Split-K bf16 MFMA flash attention (flash-decoding style).
// One wave per block.  Each block = (head h, q-tile t of 16 rows, split s)
// processing up to 4 K-chunks (256 keys).  Writes unnormalized partials:
// O_s (bf16 [16][64]), m_s, l_s (fp32 [16]) to workspace.
// nsplit(t) = t/16+1; per head sum = 576 units; grid = 16*576 = 9216.
// Unit id u = h*576 + b where b enumerates (t, s) groupwise.
// ---------------------------------------------------------------------------
__global__ __launch_bounds__(64) void attn_split(
    const u16* __restrict__ Q, const u16* __restrict__ K,
    const u16* __restrict__ Vt, u16* __restrict__ op, float* __restrict__ ml) {
  __shared__ u16 P_lds[16][72];  // [q-row][key], +8 pad
  const int lane = threadIdx.x;
  const int l15 = lane & 15;
  const int l4 = lane >> 4;       // 0..3
  const int rbase = l4 * 4;       // C-layout row base
  const int bid = blockIdx.x;
  const int h = bid & 15;
  const int b = bid >> 4;         // 0..575
  // decode (t, s): group g = t/16 has 16 tiles x (g+1) splits, base 8g(g+1)
  int g = 0;
#pragma unroll
  for (int gg = 1; gg < 8; gg++)
    if (b >= 8 * gg * (gg + 1)) g = gg;
  const int sp = g + 1;
  const int idx = b - 8 * g * (g + 1);
  const int tq = idx / sp;
  const int t = 16 * g + tq;
  const int s = idx - tq * sp;
  const int u = h * 576 + b;

  const int nc = (t >> 2) + 1;               // total chunks for this tile
  const int c0 = s * 4;
  const int c1 = min(c0 + 4, nc);
  const int qbase = t << 4;

  const u16* Qh = Q + (size_t)h * TT * DH;
  const u16* Kh = K + (size_t)h * TT * DH;
  const u16* Vh = Vt + (size_t)h * DH * TT;

  // Q A-frags in registers (2 k-steps over dh); row = lane&15
  const int qrow = qbase + l15;
  bf16x8 qf0 = *(const bf16x8*)&Qh[(size_t)qrow * DH + l4 * 8];
  bf16x8 qf1 = *(const bf16x8*)&Qh[(size_t)qrow * DH + 32 + l4 * 8];

  float m[4], l[4];
  f32x4 oacc[4];
#pragma unroll
  for (int r = 0; r < 4; r++) {
    m[r] = -1e30f;
    l[r] = 0.f;
  }
#pragma unroll
  for (int j = 0; j < 4; j++) oacc[j] = f32x4{0.f, 0.f, 0.f, 0.f};

  for (int ch = c0; ch < c1; ch++) {
    const int kbase = ch << 6;
    // ---- QK^T: S[16 q][64 keys], 8 MFMAs ----
    f32x4 s4v[4];
#pragma unroll
    for (int j = 0; j < 4; j++) s4v[j] = f32x4{0.f, 0.f, 0.f, 0.f};
#pragma unroll
    for (int j = 0; j < 4; j++) {
      bf16x8 kf0 =
          *(const bf16x8*)&Kh[(size_t)(kbase + j * 16 + l15) * DH + l4 * 8];
      bf16x8 kf1 = *(const bf16x8*)&Kh[(size_t)(kbase + j * 16 + l15) * DH +
                                       32 + l4 * 8];
      s4v[j] =
          __builtin_amdgcn_mfma_f32_16x16x32_bf16(qf0, kf0, s4v[j], 0, 0, 0);
      s4v[j] =
          __builtin_amdgcn_mfma_f32_16x16x32_bf16(qf1, kf1, s4v[j], 0, 0, 0);
    }
    // scale + causal mask (chunk nc-1 contains the diagonal)
#pragma unroll
    for (int j = 0; j < 4; j++) {
      s4v[j][0] *= 0.125f; s4v[j][1] *= 0.125f;
      s4v[j][2] *= 0.125f; s4v[j][3] *= 0.125f;
    }
    if (ch == nc - 1) {
#pragma unroll
      for (int j = 0; j < 4; j++) {
        int kg = kbase + j * 16 + l15;
#pragma unroll
        for (int r = 0; r < 4; r++) {
          int qg = qbase + rbase + r;
          if (kg > qg) s4v[j][r] = -1e30f;
        }
      }
    }
    // ---- online softmax per row (16-lane groups share rows) ----
#pragma unroll
    for (int r = 0; r < 4; r++) {
      float rm =
          fmaxf(fmaxf(s4v[0][r], s4v[1][r]), fmaxf(s4v[2][r], s4v[3][r]));
      rm = fmaxf(rm, __shfl_xor(rm, 1));
      rm = fmaxf(rm, __shfl_xor(rm, 2));
      rm = fmaxf(rm, __shfl_xor(rm, 4));
      rm = fmaxf(rm, __shfl_xor(rm, 8));
      const float mn = fmaxf(m[r], rm);
      const float corr = __expf(m[r] - mn);
      m[r] = mn;
      float rs = 0.f;
#pragma unroll
      for (int j = 0; j < 4; j++) {
        float p = __expf(s4v[j][r] - mn);
        s4v[j][r] = p;
        rs += p;
      }
      rs += __shfl_xor(rs, 1);
      rs += __shfl_xor(rs, 2);
      rs += __shfl_xor(rs, 4);
      rs += __shfl_xor(rs, 8);
      l[r] = l[r] * corr + rs;
      oacc[0][r] *= corr;
      oacc[1][r] *= corr;
      oacc[2][r] *= corr;
      oacc[3][r] *= corr;
    }
    // ---- P (bf16) to LDS re-layout; same wave, no barrier ----
#pragma unroll
    for (int j = 0; j < 4; j++)
#pragma unroll
      for (int r = 0; r < 4; r++)
        P_lds[rbase + r][j * 16 + l15] = f2bf(s4v[j][r]);
    // ---- PV: O[16 q][64 dh] += P @ V, 8 MFMAs ----
#pragma unroll
    for (int ks = 0; ks < 2; ks++) {
      bf16x8 pa = *(const bf16x8*)&P_lds[l15][ks * 32 + l4 * 8];
#pragma unroll
      for (int j = 0; j < 4; j++) {
        bf16x8 vf = *(const bf16x8*)&Vh[(size_t)(j * 16 + l15) * TT + kbase +
                                        ks * 32 + l4 * 8];
        oacc[j] =
            __builtin_amdgcn_mfma_f32_16x16x32_bf16(pa, vf, oacc[j], 0, 0, 0);
      }
    }
  }
  // ---- store partials (unnormalized) ----
  if (l15 == 0) {
#pragma unroll
    for (int r = 0; r < 4; r++) {
      ml[(size_t)u * 32 + rbase + r] = m[r];
      ml[(size_t)u * 32 + 16 + rbase + r] = l[r];
    }
  }
  u16* ou = op + (size_t)u * 1024;
#pragma unroll
  for (int j = 0; j < 4; j++)
#pragma unroll
    for (int r = 0; r < 4; r++)
      ou[(rbase + r) * 64 + j * 16 + l15] = f2bf(oacc[j][r]);
}

// ---------------------------------------------------------------------------
// Combine splits: O = sum_s exp(m_s-m)*O_s ; l = sum_s exp(m_s-m)*l_s.
// One wave per (h, t); lane owns row=lane>>2, cols (lane&3)*16..+15.
// Writes final bf16 [T][E].
// ---------------------------------------------------------------------------
__global__ __launch_bounds__(64) void attn_combine(
    const u16* __restrict__ op, const float* __restrict__ ml,
    u16* __restrict__ O) {
  const int lane = threadIdx.x;
  const int row = lane >> 2;       // 0..15
  const int c0 = (lane & 3) * 16;  // 16 cols per lane
  const int h = blockIdx.x & 15;
  const int t = blockIdx.x >> 4;
  const int g = t >> 4;
  const int ns = g + 1;
  const int u0 = h * 576 + 8 * g * (g + 1) + (t - 16 * g) * ns;

  float mg = -1e30f;
  for (int s = 0; s < ns; s++)
    mg = fmaxf(mg, ml[(size_t)(u0 + s) * 32 + row]);
  float acc[16];
#pragma unroll
  for (int i = 0; i < 16; i++) acc[i] = 0.f;
  float lg = 0.f;
  for (int s = 0; s < ns; s++) {
    const size_t u = u0 + s;
    const float w = __expf(ml[u * 32 + row] - mg);
    lg += w * ml[u * 32 + 16 + row];
    const u16* po = op + u * 1024 + row * 64 + c0;
    bf16x8 v0 = *(const bf16x8*)po;
    bf16x8 v1 = *(const bf16x8*)(po + 8);
#pragma unroll
    for (int i = 0; i < 8; i++) {
      acc[i] += w * bf2f((u16)v0[i]);
      acc[8 + i] += w * bf2f((u16)v1[i]);
    }
  }
  const float inv = 1.f / lg;
  const int qg = (t << 4) + row;
  u16* dst = O + (size_t)qg * EE + h * DH + c0;
#pragma unroll
  for (int i = 0; i < 16; i++) dst[i] = f2bf(acc[i] * inv);
}

// ---------------------------------------------------------------------------
extern "C" void kernel_launch(void* const* d_in, const int* in_sizes, int n_in,
                              void* d_out, int out_size, void* d_ws,
                              size_t ws_size, hipStream_t stream) {
  const float* x = (const float*)d_in[0];    // [2048][1024]
  const float* W1 = (const float*)d_in[1];   // [3072][1024]
  const float* W2 = (const float*)d_in[2];   // [1024][1024]
  float* out = (float*)d_out;                // [2048][1024]

  float* ws = (float*)d_ws;
  const size_t HTD = (size_t)HH * TT * DH;   // 2,097,152
  float* cs = ws;
  float* sn = cs + (size_t)TT * 32;
  float* ml = sn + (size_t)TT * 32;          // [9216][32] fp32 partial m,l
  u16* qb16 = (u16*)(ml + (size_t)9216 * 32);  // bf16 roped q [H][T][DH]
  u16* kb16 = qb16 + HTD;                    // bf16 roped k
  u16* vt16 = kb16 + HTD;                    // bf16 v transposed [H][DH][T]
  u16* obb = vt16 + HTD;                     // bf16 attn out [T][E]
  u16* xb = obb + (size_t)TT * EE;           // bf16 inputs
  u16* w1b = xb + (size_t)TT * EE;
  u16* w2b = w1b + (size_t)3 * EE * EE;
  u16* op = w2b + (size_t)EE * EE;           // [9216][1024] bf16 partial O

  rope_table<<<(TT * 32) / 256, 256, 0, stream>>>(cs, sn);
  cvt_all<<<786432 / 256, 256, 0, stream>>>(x, W1, W2, xb, w1b, w2b);
  // QKV: [2048 x 3072] = x @ W1^T;  q,k roped bf16; v bf16 transposed
  gemm_mfma<1><<<dim3(3 * EE / 128, TT / 128), 256, 0, stream>>>(
      xb, w1b, nullptr, qb16, kb16, vt16, cs, sn, TT, 3 * EE, EE);
  attn_split<<<9216, 64, 0, stream>>>(qb16, kb16, vt16, op, ml);
  attn_combine<<<2048, 64, 0, stream>>>(op, ml, obb);
  // proj: [2048 x 1024] = attn @ W2^T
  gemm_mfma<0><<<dim3(EE / 128, TT / 128), 256, 0, stream>>>(
      obb, w2b, out, nullptr, nullptr, nullptr, nullptr, nullptr, TT, EE, EE);
}